// Round 4
// baseline (152.255 us; speedup 1.0000x reference)
//
#include <hip/hip_runtime.h>

typedef __attribute__((ext_vector_type(8))) __bf16 bf16x8;
typedef __attribute__((ext_vector_type(4))) float f32x4;
typedef unsigned short u16;
typedef unsigned int u32;

#define VMCNT(n) asm volatile("s_waitcnt vmcnt(" #n ")" ::: "memory")

__device__ __forceinline__ u16 f2bf(float f) {
  union { float f; u32 u; } v; v.f = f;
  u32 r = v.u + 0x7FFFu + ((v.u >> 16) & 1u);
  return (u16)(r >> 16);
}
__device__ __forceinline__ float fexp2(float x) {  // 2^x via v_exp_f32
  float r; asm("v_exp_f32 %0, %1" : "=v"(r) : "v"(x)); return r;
}

// ---------------- cast x fp32 -> bf16 (4 elems/thread) ----------------
__global__ __launch_bounds__(256) void cast_x_kernel(const float* __restrict__ x,
                                                     u16* __restrict__ xb, int n4) {
  int i = blockIdx.x * 256 + threadIdx.x;
  if (i >= n4) return;
  float4 v = reinterpret_cast<const float4*>(x)[i];
  ushort4 o;
  o.x = f2bf(v.x); o.y = f2bf(v.y); o.z = f2bf(v.z); o.w = f2bf(v.w);
  reinterpret_cast<ushort4*>(xb)[i] = o;
}

// ------- transpose weights: Wt[u][d] = W[d][u], fp32 -> bf16 ----------
__global__ __launch_bounds__(1024) void transpose_w_kernel(const float* __restrict__ Wq,
                                                           const float* __restrict__ Wk,
                                                           const float* __restrict__ Wv,
                                                           u16* __restrict__ Wt) {
  const float* src = blockIdx.z == 0 ? Wq : (blockIdx.z == 1 ? Wk : Wv);
  u16* dst = Wt + (size_t)blockIdx.z * 512 * 512;
  __shared__ float tile[32][33];
  int u0 = blockIdx.x * 32, d0 = blockIdx.y * 32;
  tile[threadIdx.y][threadIdx.x] = src[(d0 + threadIdx.y) * 512 + u0 + threadIdx.x];
  __syncthreads();
  dst[(u0 + threadIdx.y) * 512 + d0 + threadIdx.x] = f2bf(tile[threadIdx.x][threadIdx.y]);
}

// ---------------- QKV projection: 128x128 tile, ring-3 counted-vmcnt ----
// z==2 (V) writes Vt2[b][kt][u][32] (kt = s>>5): pv stages contiguous tiles.
__global__ __launch_bounds__(256) void qkv_kernel(const u16* __restrict__ Xb,
                                                  const u16* __restrict__ Wt3,
                                                  u16* __restrict__ Q, u16* __restrict__ K,
                                                  u16* __restrict__ Vt2) {
  __shared__ u16 As[3][128 * 32], Bs[3][128 * 32];
  const int bm = blockIdx.y * 128;
  const int bn = blockIdx.x * 128;
  const int z = blockIdx.z;
  const u16* A = Xb + (size_t)bm * 512;
  const u16* Bt = Wt3 + (size_t)z * 512 * 512 + (size_t)bn * 512;

  const int t = threadIdx.x;
  const int lane = t & 63;
  const int w = t >> 6;
  const int wr = w >> 1, wc = w & 1;
  const int la = lane & 15;
  const int q = lane >> 4;
  f32x4 acc[4][4] = {};

  auto stage = [&](int buf, int kt) {
    const int k0 = kt * 32;
#pragma unroll
    for (int it = 0; it < 2; ++it) {    // A: 128 rows -> 512 chunks
      int c = it * 256 + t, row = c >> 2;
      int col = ((c & 3) ^ ((row >> 1) & 3)) << 3;
      __builtin_amdgcn_global_load_lds(
          (const __attribute__((address_space(1))) void*)(A + (size_t)row * 512 + k0 + col),
          (__attribute__((address_space(3))) void*)(&As[buf][c * 8]), 16, 0, 0);
    }
#pragma unroll
    for (int it = 0; it < 2; ++it) {    // B: 128 rows -> 512 chunks
      int c = it * 256 + t, row = c >> 2;
      int col = ((c & 3) ^ ((row >> 1) & 3)) << 3;
      __builtin_amdgcn_global_load_lds(
          (const __attribute__((address_space(1))) void*)(Bt + (size_t)row * 512 + k0 + col),
          (__attribute__((address_space(3))) void*)(&Bs[buf][c * 8]), 16, 0, 0);
    }
  };

  auto body = [&](int buf) {
    bf16x8 a[4], b[4];
#pragma unroll
    for (int i = 0; i < 4; ++i) {
      int row = wr * 64 + i * 16 + la;
      a[i] = *reinterpret_cast<const bf16x8*>(&As[buf][row * 32 + ((q ^ ((row >> 1) & 3)) << 3)]);
    }
#pragma unroll
    for (int j = 0; j < 4; ++j) {
      int row = wc * 64 + j * 16 + la;
      b[j] = *reinterpret_cast<const bf16x8*>(&Bs[buf][row * 32 + ((q ^ ((row >> 1) & 3)) << 3)]);
    }
    __builtin_amdgcn_s_setprio(1);
#pragma unroll
    for (int i = 0; i < 4; ++i)
#pragma unroll
      for (int j = 0; j < 4; ++j)
        acc[i][j] = __builtin_amdgcn_mfma_f32_16x16x32_bf16(a[i], b[j], acc[i][j], 0, 0, 0);
    __builtin_amdgcn_s_setprio(0);
  };

  stage(0, 0); stage(1, 1);             // 8 loads/thread in flight
  int cb = 0, sb = 2;
  for (int kt = 0; kt < 14; ++kt) {
    VMCNT(4);                           // tile kt landed; kt+1 flying
    __builtin_amdgcn_s_barrier();       // all waves' kt landed; buf sb free
    stage(sb, kt + 2);
    body(cb);
    cb = (cb == 2) ? 0 : cb + 1;
    sb = (sb == 2) ? 0 : sb + 1;
  }
  VMCNT(4); __builtin_amdgcn_s_barrier(); body(2);   // kt=14 -> buf 14%3=2
  VMCNT(0); __builtin_amdgcn_s_barrier(); body(0);   // kt=15 -> buf 0

  const int r0 = q * 4, cn = lane & 15;
  if (z < 2) {
    u16* out = (z == 0) ? Q : K;
#pragma unroll
    for (int i = 0; i < 4; ++i)
#pragma unroll
      for (int j = 0; j < 4; ++j)
#pragma unroll
        for (int r = 0; r < 4; ++r) {
          int m = bm + 64 * wr + 16 * i + r0 + r;
          int n = bn + 64 * wc + 16 * j + cn;
          out[(size_t)m * 512 + n] = f2bf(acc[i][j][r]);
        }
  } else {
#pragma unroll
    for (int i = 0; i < 4; ++i)
#pragma unroll
      for (int j = 0; j < 4; ++j)
#pragma unroll
        for (int r = 0; r < 4; ++r) {
          int m = bm + 64 * wr + 16 * i + r0 + r;
          int u = bn + 64 * wc + 16 * j + cn;
          int b = m >> 11, s = m & 2047;
          // Vt2[b][kt=s>>5][u][s&31]
          Vt2[(((size_t)b * 64 + (s >> 5)) * 512 + u) * 32 + (s & 31)] = f2bf(acc[i][j][r]);
        }
  }
}

// ------ P = exp(Q K^T / sqrt(512)) -> bf16: 256x256, ring-4 ------
// Output layout S2[b][kt][q][32] (kt = k>>5): pv stages contiguous tiles.
__global__ __launch_bounds__(512) void scores8_kernel(const u16* __restrict__ Q,
                                                      const u16* __restrict__ K,
                                                      u16* __restrict__ S2) {
  __shared__ u16 ring[4][2][256 * 32];  // [buf][A=0/B=1][256 rows][32 k]
  const int bb = blockIdx.x;            // batch -> XCD
  const int bm = blockIdx.y * 256;
  const int bn = blockIdx.z * 256;
  const u16* Aq = Q + (size_t)(bb * 2048 + bm) * 512;
  const u16* Bk = K + (size_t)(bb * 2048 + bn) * 512;

  const int t = threadIdx.x;
  const int lane = t & 63;
  const int wid = t >> 6;
  const int wm = wid >> 2, wn = wid & 3;
  const int la = lane & 15;
  const int q = lane >> 4;              // k-slot 0..3 (8 elems each)

  f32x4 acc[8][4] = {};

  auto stage = [&](int kt) {
    const int r = kt & 3;
    const int koff = kt * 32;
#pragma unroll
    for (int half = 0; half < 2; ++half) {
      int c = half * 512 + t;
      int row = c >> 2;
      int col = ((c & 3) ^ ((row >> 1) & 3)) << 3;   // inverse swizzle on source
      __builtin_amdgcn_global_load_lds(
          (const __attribute__((address_space(1))) void*)(Aq + (size_t)row * 512 + koff + col),
          (__attribute__((address_space(3))) void*)(&ring[r][0][c * 8]), 16, 0, 0);
      __builtin_amdgcn_global_load_lds(
          (const __attribute__((address_space(1))) void*)(Bk + (size_t)row * 512 + koff + col),
          (__attribute__((address_space(3))) void*)(&ring[r][1][c * 8]), 16, 0, 0);
    }
  };

  auto body = [&](int kt) {
    const int r = kt & 3;
    const u16* At = ring[r][0];
    const u16* Bt = ring[r][1];
    bf16x8 bfr[4], afr[8];
#pragma unroll
    for (int j = 0; j < 4; ++j) {
      int row = wn * 64 + j * 16 + la;
      bfr[j] = *reinterpret_cast<const bf16x8*>(Bt + row * 32 + ((q ^ ((row >> 1) & 3)) << 3));
    }
#pragma unroll
    for (int i = 0; i < 8; ++i) {
      int row = wm * 128 + i * 16 + la;
      afr[i] = *reinterpret_cast<const bf16x8*>(At + row * 32 + ((q ^ ((row >> 1) & 3)) << 3));
    }
    __builtin_amdgcn_s_setprio(1);
#pragma unroll
    for (int i = 0; i < 8; ++i)
#pragma unroll
      for (int j = 0; j < 4; ++j)
        acc[i][j] = __builtin_amdgcn_mfma_f32_16x16x32_bf16(afr[i], bfr[j], acc[i][j], 0, 0, 0);
    __builtin_amdgcn_s_setprio(0);
  };

  stage(0); stage(1); stage(2);         // 12 loads/thread in flight
  for (int kt = 0; kt < 13; ++kt) {
    VMCNT(8);                           // kt's 4 loads landed; kt+1/kt+2 fly
    __builtin_amdgcn_s_barrier();       // all waves' kt landed; buf[(kt+3)&3] free
    stage(kt + 3);
    body(kt);
  }
  VMCNT(8); __builtin_amdgcn_s_barrier(); body(13);
  VMCNT(4); __builtin_amdgcn_s_barrier(); body(14);
  VMCNT(0); __builtin_amdgcn_s_barrier(); body(15);

  const float scale = 0.06375872127f;   // log2(e)/sqrt(512)
  const int r0h = q * 4;
#pragma unroll
  for (int i = 0; i < 8; ++i)
#pragma unroll
    for (int j = 0; j < 4; ++j) {
      int n = bn + wn * 64 + j * 16;                 // k-col base (la added below)
      int kt_j = n >> 5;
      int ke_j = (n & 31) + la;                      // no carry: (n&31) in {0,16}, la<16
      u16* dst = S2 + ((size_t)(bb * 64 + kt_j) * 2048) * 32 + ke_j;
#pragma unroll
      for (int r = 0; r < 4; ++r) {
        int m = bm + wm * 128 + i * 16 + r0h + r;
        dst[(size_t)m * 32] = f2bf(fexp2(acc[i][j][r] * scale));
      }
    }
}

// ---- out = (P * V) / rowsum(P): 256x128 tile, BK=64, ring-3 ----
// Round-3 post-mortem: per-block-K-step wall time is ~2330cy in BOTH pv
// (128 MFMA/CU-step) and scores8 (256 MFMA/CU-step) -> 2-phase structure
// has a FIXED per-step overhead; only amortization helps. Reshape pv to
// scores8's per-CU profile: 512 thr / 8 waves (64q x 64u each), BK=64
// (two 32-k subtiles per barrier), 32 steps, 256 MFMA/CU-step.
// LDS ring-3 x (256+128)x64x2B = 144KB -> 1 block/CU; grid 256 = 1/CU.
__global__ __launch_bounds__(512) void pv_kernel(const u16* __restrict__ S2,
                                                 const u16* __restrict__ Vt2,
                                                 float* __restrict__ out) {
  __shared__ u16 As[3][2][256 * 32];    // [buf][k-half][256 q][32 k]
  __shared__ u16 Bs[3][2][128 * 32];    // [buf][k-half][128 u][32 k]
  __shared__ float larr[256];
  const int id = blockIdx.x;
  const int b = id & 7;                 // batch == XCD
  const int local = id >> 3;            // 0..31
  const int bn = (local & 3) * 128;     // u cols
  const int bm = (local >> 2) * 256;    // q rows

  // S2[b][kt][q][32]: tile base (b,kt,bm) = A2 + kt*65536 (+row*32)
  const u16* A2 = S2 + ((size_t)b * 64 * 2048 + (size_t)bm) * 32;
  // Vt2[b][kt][u][32]: tile base (b,kt,bn) = B2 + kt*16384 (+row*32)
  const u16* B2 = Vt2 + ((size_t)b * 64 * 512 + (size_t)bn) * 32;

  const int t = threadIdx.x;            // 0..511
  const int lane = t & 63;
  const int wid = t >> 6;               // 0..7
  const int wm = wid >> 1;              // 0..3: q 64-row block
  const int wn = wid & 1;               // 0..1: u 64-col block
  const int la = lane & 15;
  const int q = lane >> 4;

  f32x4 acc[4][4] = {};
  float lacc[4] = {0.f, 0.f, 0.f, 0.f};

  auto stage = [&](int s) {             // stages k-tiles 2s and 2s+1
    const int buf = s % 3;
#pragma unroll
    for (int it = 0; it < 4; ++it) {    // A: 2 halves x 1024 chunks
      int c = it * 512 + t;             // 0..2047; h=c>>10 wave-uniform
      int h = c >> 10;
      int idx = c & 1023;
      int row = idx >> 2;
      int col = ((c & 3) ^ ((row >> 1) & 3)) << 3;
      __builtin_amdgcn_global_load_lds(
          (const __attribute__((address_space(1))) void*)(A2 + (size_t)(2 * s + h) * 65536 + row * 32 + col),
          (__attribute__((address_space(3))) void*)(&As[buf][0][c * 8]), 16, 0, 0);
    }
#pragma unroll
    for (int it = 0; it < 2; ++it) {    // B: 2 halves x 512 chunks
      int c = it * 512 + t;             // 0..1023; h=c>>9 wave-uniform
      int h = c >> 9;
      int idx = c & 511;
      int row = idx >> 2;
      int col = ((c & 3) ^ ((row >> 1) & 3)) << 3;
      __builtin_amdgcn_global_load_lds(
          (const __attribute__((address_space(1))) void*)(B2 + (size_t)(2 * s + h) * 16384 + row * 32 + col),
          (__attribute__((address_space(3))) void*)(&Bs[buf][0][c * 8]), 16, 0, 0);
    }
  };

  auto body = [&](int s) {
    const int buf = s % 3;
#pragma unroll
    for (int h = 0; h < 2; ++h) {
      const u16* Ah = &As[buf][h][0];
      const u16* Bh = &Bs[buf][h][0];
      bf16x8 a[4], bb[4];
#pragma unroll
      for (int i = 0; i < 4; ++i) {
        int row = wm * 64 + i * 16 + la;
        a[i] = *reinterpret_cast<const bf16x8*>(Ah + row * 32 + ((q ^ ((row >> 1) & 3)) << 3));
      }
      if (wn == 0) {                    // count each P element exactly once
#pragma unroll
        for (int i = 0; i < 4; ++i) {
          float ls = 0.f;
#pragma unroll
          for (int e = 0; e < 8; ++e) ls += (float)a[i][e];
          lacc[i] += ls;
        }
      }
#pragma unroll
      for (int j = 0; j < 4; ++j) {
        int row = wn * 64 + j * 16 + la;
        bb[j] = *reinterpret_cast<const bf16x8*>(Bh + row * 32 + ((q ^ ((row >> 1) & 3)) << 3));
      }
      __builtin_amdgcn_s_setprio(1);
#pragma unroll
      for (int i = 0; i < 4; ++i)
#pragma unroll
        for (int j = 0; j < 4; ++j)
          acc[i][j] = __builtin_amdgcn_mfma_f32_16x16x32_bf16(a[i], bb[j], acc[i][j], 0, 0, 0);
      __builtin_amdgcn_s_setprio(0);
    }
  };

  stage(0); stage(1);                   // 12 loads/thread in flight
  for (int s = 0; s < 30; ++s) {
    VMCNT(6);                           // step s landed; s+1 flying
    __builtin_amdgcn_s_barrier();       // all waves' s landed; buf (s+2)%3 free
    stage(s + 2);
    body(s);
  }
  VMCNT(6); __builtin_amdgcn_s_barrier(); body(30);  // buf 0
  VMCNT(0); __builtin_amdgcn_s_barrier(); body(31);  // buf 1

  // ---- epilogue: reduce row partials over q-lanes, normalize, store ---
  float l[4];
#pragma unroll
  for (int i = 0; i < 4; ++i) {
    l[i] = lacc[i];
    l[i] += __shfl_xor(l[i], 16);
    l[i] += __shfl_xor(l[i], 32);       // sum across 4 q-lanes (la preserved)
  }
  if (wn == 0 && q == 0) {              // writers: 4 wm x 16 la x 4 i = 256 rows
#pragma unroll
    for (int i = 0; i < 4; ++i) larr[wm * 64 + i * 16 + la] = l[i];
  }
  __syncthreads();

  float* C = out + ((size_t)b * 2048 + bm) * 512;
  const int r0 = q * 4, cn = lane & 15;
  float inv[4][4];
#pragma unroll
  for (int i = 0; i < 4; ++i)
#pragma unroll
    for (int r = 0; r < 4; ++r)
      inv[i][r] = 1.0f / larr[wm * 64 + i * 16 + r0 + r];
#pragma unroll
  for (int i = 0; i < 4; ++i)
#pragma unroll
    for (int j = 0; j < 4; ++j)
#pragma unroll
      for (int r = 0; r < 4; ++r) {
        int m = wm * 64 + 16 * i + r0 + r;
        int n = bn + 64 * wn + 16 * j + cn;
        C[(size_t)m * 512 + n] = acc[i][j][r] * inv[i][r];
      }
}

extern "C" void kernel_launch(void* const* d_in, const int* in_sizes, int n_in,
                              void* d_out, int out_size, void* d_ws, size_t ws_size,
                              hipStream_t stream) {
  const float* x  = (const float*)d_in[0];
  const float* Wq = (const float*)d_in[1];
  const float* Wk = (const float*)d_in[2];
  const float* Wv = (const float*)d_in[3];
  float* out = (float*)d_out;

  // ws layout: Xb bf16[16384][512] | Wt bf16[3][512][512] | Q | K | Vt2 | S2
  char* p = (char*)d_ws;
  u16* Xb = (u16*)p;            p += (size_t)16384 * 512 * 2;
  u16* Wt = (u16*)p;            p += (size_t)3 * 512 * 512 * 2;
  u16* Q  = (u16*)p;            p += (size_t)16384 * 512 * 2;
  u16* K  = (u16*)p;            p += (size_t)16384 * 512 * 2;
  u16* Vt2 = (u16*)p;           p += (size_t)16384 * 512 * 2;
  u16* S2 = (u16*)p;

  cast_x_kernel<<<dim3(8192), dim3(256), 0, stream>>>(x, Xb, 16384 * 512 / 4);
  transpose_w_kernel<<<dim3(16, 16, 3), dim3(32, 32), 0, stream>>>(Wq, Wk, Wv, Wt);
  qkv_kernel<<<dim3(4, 128, 3), dim3(256), 0, stream>>>(Xb, Wt, Q, K, Vt2);
  scores8_kernel<<<dim3(8, 8, 8), dim3(512), 0, stream>>>(Q, K, S2);
  pv_kernel<<<dim3(256), dim3(512), 0, stream>>>(S2, Vt2, out);
}

// Round 5
// 148.062 us; speedup vs baseline: 1.0283x; 1.0283x over previous
//
#include <hip/hip_runtime.h>

typedef __attribute__((ext_vector_type(8))) __bf16 bf16x8;
typedef __attribute__((ext_vector_type(4))) float f32x4;
typedef unsigned short u16;
typedef unsigned int u32;

#define VMCNT(n) asm volatile("s_waitcnt vmcnt(" #n ")" ::: "memory")

__device__ __forceinline__ u16 f2bf(float f) {
  union { float f; u32 u; } v; v.f = f;
  u32 r = v.u + 0x7FFFu + ((v.u >> 16) & 1u);
  return (u16)(r >> 16);
}
__device__ __forceinline__ float fexp2(float x) {  // 2^x via v_exp_f32
  float r; asm("v_exp_f32 %0, %1" : "=v"(r) : "v"(x)); return r;
}

// ---------------- cast x fp32 -> bf16 (4 elems/thread) ----------------
__global__ __launch_bounds__(256) void cast_x_kernel(const float* __restrict__ x,
                                                     u16* __restrict__ xb, int n4) {
  int i = blockIdx.x * 256 + threadIdx.x;
  if (i >= n4) return;
  float4 v = reinterpret_cast<const float4*>(x)[i];
  ushort4 o;
  o.x = f2bf(v.x); o.y = f2bf(v.y); o.z = f2bf(v.z); o.w = f2bf(v.w);
  reinterpret_cast<ushort4*>(xb)[i] = o;
}

// ------- transpose weights: Wt[u][d] = W[d][u], fp32 -> bf16 ----------
__global__ __launch_bounds__(1024) void transpose_w_kernel(const float* __restrict__ Wq,
                                                           const float* __restrict__ Wk,
                                                           const float* __restrict__ Wv,
                                                           u16* __restrict__ Wt) {
  const float* src = blockIdx.z == 0 ? Wq : (blockIdx.z == 1 ? Wk : Wv);
  u16* dst = Wt + (size_t)blockIdx.z * 512 * 512;
  __shared__ float tile[32][33];
  int u0 = blockIdx.x * 32, d0 = blockIdx.y * 32;
  tile[threadIdx.y][threadIdx.x] = src[(d0 + threadIdx.y) * 512 + u0 + threadIdx.x];
  __syncthreads();
  dst[(u0 + threadIdx.y) * 512 + d0 + threadIdx.x] = f2bf(tile[threadIdx.x][threadIdx.y]);
}

// ---------------- QKV projection: 128x128 tile, ring-3 counted-vmcnt ----
// z==2 (V) writes Vt2[b][kt][u][32] (kt = s>>5): pv stages contiguous tiles.
__global__ __launch_bounds__(256) void qkv_kernel(const u16* __restrict__ Xb,
                                                  const u16* __restrict__ Wt3,
                                                  u16* __restrict__ Q, u16* __restrict__ K,
                                                  u16* __restrict__ Vt2) {
  __shared__ u16 As[3][128 * 32], Bs[3][128 * 32];
  const int bm = blockIdx.y * 128;
  const int bn = blockIdx.x * 128;
  const int z = blockIdx.z;
  const u16* A = Xb + (size_t)bm * 512;
  const u16* Bt = Wt3 + (size_t)z * 512 * 512 + (size_t)bn * 512;

  const int t = threadIdx.x;
  const int lane = t & 63;
  const int w = t >> 6;
  const int wr = w >> 1, wc = w & 1;
  const int la = lane & 15;
  const int q = lane >> 4;
  f32x4 acc[4][4] = {};

  auto stage = [&](int buf, int kt) {
    const int k0 = kt * 32;
#pragma unroll
    for (int it = 0; it < 2; ++it) {    // A: 128 rows -> 512 chunks
      int c = it * 256 + t, row = c >> 2;
      int col = ((c & 3) ^ ((row >> 1) & 3)) << 3;
      __builtin_amdgcn_global_load_lds(
          (const __attribute__((address_space(1))) void*)(A + (size_t)row * 512 + k0 + col),
          (__attribute__((address_space(3))) void*)(&As[buf][c * 8]), 16, 0, 0);
    }
#pragma unroll
    for (int it = 0; it < 2; ++it) {    // B: 128 rows -> 512 chunks
      int c = it * 256 + t, row = c >> 2;
      int col = ((c & 3) ^ ((row >> 1) & 3)) << 3;
      __builtin_amdgcn_global_load_lds(
          (const __attribute__((address_space(1))) void*)(Bt + (size_t)row * 512 + k0 + col),
          (__attribute__((address_space(3))) void*)(&Bs[buf][c * 8]), 16, 0, 0);
    }
  };

  auto body = [&](int buf) {
    bf16x8 a[4], b[4];
#pragma unroll
    for (int i = 0; i < 4; ++i) {
      int row = wr * 64 + i * 16 + la;
      a[i] = *reinterpret_cast<const bf16x8*>(&As[buf][row * 32 + ((q ^ ((row >> 1) & 3)) << 3)]);
    }
#pragma unroll
    for (int j = 0; j < 4; ++j) {
      int row = wc * 64 + j * 16 + la;
      b[j] = *reinterpret_cast<const bf16x8*>(&Bs[buf][row * 32 + ((q ^ ((row >> 1) & 3)) << 3)]);
    }
    __builtin_amdgcn_s_setprio(1);
#pragma unroll
    for (int i = 0; i < 4; ++i)
#pragma unroll
      for (int j = 0; j < 4; ++j)
        acc[i][j] = __builtin_amdgcn_mfma_f32_16x16x32_bf16(a[i], b[j], acc[i][j], 0, 0, 0);
    __builtin_amdgcn_s_setprio(0);
  };

  stage(0, 0); stage(1, 1);             // 8 loads/thread in flight
  int cb = 0, sb = 2;
  for (int kt = 0; kt < 14; ++kt) {
    VMCNT(4);                           // tile kt landed; kt+1 flying
    __builtin_amdgcn_s_barrier();       // all waves' kt landed; buf sb free
    stage(sb, kt + 2);
    body(cb);
    cb = (cb == 2) ? 0 : cb + 1;
    sb = (sb == 2) ? 0 : sb + 1;
  }
  VMCNT(4); __builtin_amdgcn_s_barrier(); body(2);   // kt=14 -> buf 14%3=2
  VMCNT(0); __builtin_amdgcn_s_barrier(); body(0);   // kt=15 -> buf 0

  const int r0 = q * 4, cn = lane & 15;
  if (z < 2) {
    u16* out = (z == 0) ? Q : K;
#pragma unroll
    for (int i = 0; i < 4; ++i)
#pragma unroll
      for (int j = 0; j < 4; ++j)
#pragma unroll
        for (int r = 0; r < 4; ++r) {
          int m = bm + 64 * wr + 16 * i + r0 + r;
          int n = bn + 64 * wc + 16 * j + cn;
          out[(size_t)m * 512 + n] = f2bf(acc[i][j][r]);
        }
  } else {
#pragma unroll
    for (int i = 0; i < 4; ++i)
#pragma unroll
      for (int j = 0; j < 4; ++j)
#pragma unroll
        for (int r = 0; r < 4; ++r) {
          int m = bm + 64 * wr + 16 * i + r0 + r;
          int u = bn + 64 * wc + 16 * j + cn;
          int b = m >> 11, s = m & 2047;
          // Vt2[b][kt=s>>5][u][s&31]
          Vt2[(((size_t)b * 64 + (s >> 5)) * 512 + u) * 32 + (s & 31)] = f2bf(acc[i][j][r]);
        }
  }
}

// ------ P = exp(Q K^T / sqrt(512)) -> bf16: 256x256, ring-4 ------
// Output layout S2[b][kt][q][32] (kt = k>>5): pv stages contiguous tiles.
__global__ __launch_bounds__(512) void scores8_kernel(const u16* __restrict__ Q,
                                                      const u16* __restrict__ K,
                                                      u16* __restrict__ S2) {
  __shared__ u16 ring[4][2][256 * 32];  // [buf][A=0/B=1][256 rows][32 k]
  const int bb = blockIdx.x;            // batch -> XCD
  const int bm = blockIdx.y * 256;
  const int bn = blockIdx.z * 256;
  const u16* Aq = Q + (size_t)(bb * 2048 + bm) * 512;
  const u16* Bk = K + (size_t)(bb * 2048 + bn) * 512;

  const int t = threadIdx.x;
  const int lane = t & 63;
  const int wid = t >> 6;
  const int wm = wid >> 2, wn = wid & 3;
  const int la = lane & 15;
  const int q = lane >> 4;              // k-slot 0..3 (8 elems each)

  f32x4 acc[8][4] = {};

  auto stage = [&](int kt) {
    const int r = kt & 3;
    const int koff = kt * 32;
#pragma unroll
    for (int half = 0; half < 2; ++half) {
      int c = half * 512 + t;
      int row = c >> 2;
      int col = ((c & 3) ^ ((row >> 1) & 3)) << 3;   // inverse swizzle on source
      __builtin_amdgcn_global_load_lds(
          (const __attribute__((address_space(1))) void*)(Aq + (size_t)row * 512 + koff + col),
          (__attribute__((address_space(3))) void*)(&ring[r][0][c * 8]), 16, 0, 0);
      __builtin_amdgcn_global_load_lds(
          (const __attribute__((address_space(1))) void*)(Bk + (size_t)row * 512 + koff + col),
          (__attribute__((address_space(3))) void*)(&ring[r][1][c * 8]), 16, 0, 0);
    }
  };

  auto body = [&](int kt) {
    const int r = kt & 3;
    const u16* At = ring[r][0];
    const u16* Bt = ring[r][1];
    bf16x8 bfr[4], afr[8];
#pragma unroll
    for (int j = 0; j < 4; ++j) {
      int row = wn * 64 + j * 16 + la;
      bfr[j] = *reinterpret_cast<const bf16x8*>(Bt + row * 32 + ((q ^ ((row >> 1) & 3)) << 3));
    }
#pragma unroll
    for (int i = 0; i < 8; ++i) {
      int row = wm * 128 + i * 16 + la;
      afr[i] = *reinterpret_cast<const bf16x8*>(At + row * 32 + ((q ^ ((row >> 1) & 3)) << 3));
    }
    __builtin_amdgcn_s_setprio(1);
#pragma unroll
    for (int i = 0; i < 8; ++i)
#pragma unroll
      for (int j = 0; j < 4; ++j)
        acc[i][j] = __builtin_amdgcn_mfma_f32_16x16x32_bf16(afr[i], bfr[j], acc[i][j], 0, 0, 0);
    __builtin_amdgcn_s_setprio(0);
  };

  stage(0); stage(1); stage(2);         // 12 loads/thread in flight
  for (int kt = 0; kt < 13; ++kt) {
    VMCNT(8);                           // kt's 4 loads landed; kt+1/kt+2 fly
    __builtin_amdgcn_s_barrier();       // all waves' kt landed; buf[(kt+3)&3] free
    stage(kt + 3);
    body(kt);
  }
  VMCNT(8); __builtin_amdgcn_s_barrier(); body(13);
  VMCNT(4); __builtin_amdgcn_s_barrier(); body(14);
  VMCNT(0); __builtin_amdgcn_s_barrier(); body(15);

  const float scale = 0.06375872127f;   // log2(e)/sqrt(512)
  const int r0h = q * 4;
#pragma unroll
  for (int i = 0; i < 8; ++i)
#pragma unroll
    for (int j = 0; j < 4; ++j) {
      int n = bn + wn * 64 + j * 16;                 // k-col base (la added below)
      int kt_j = n >> 5;
      int ke_j = (n & 31) + la;                      // no carry: (n&31) in {0,16}, la<16
      u16* dst = S2 + ((size_t)(bb * 64 + kt_j) * 2048) * 32 + ke_j;
#pragma unroll
      for (int r = 0; r < 4; ++r) {
        int m = bm + wm * 128 + i * 16 + r0h + r;
        dst[(size_t)m * 32] = f2bf(fexp2(acc[i][j][r] * scale));
      }
    }
}

// ---- out = (P * V) / rowsum(P): 256x128 tile, BK=64, ring-3, 8-PHASE ----
// Round-4 post-mortem: per-step cost SCALES with staged volume in the
// 2-phase structure (m233: stage+vmcnt+bar = ~72% of critical path,
// ceiling ~600 TF; we sit at 555). Exit is structural: T3+T4 8-phase
// counted-vmcnt interleave (prereq for T2/T5 to pay). This kernel keeps
// round-4's proven geometry/fragments (512thr, 8 waves of 64x64, BK=64,
// ring-3) and splits each K-step into 4 quadrant-phases:
//   {ds_read subset || 1-2 global_load_lds || bar || setprio 8-MFMA || bar}
// vmcnt ledger: 6 loads/thread/tile. At step-s phase-4: outstanding =
// {tile s+1: 6, tile s+2: 6} -> VMCNT(6) => s+1 landed; barrier makes it
// collective before step s+1's reads. Never 0 in main loop.
__global__ __launch_bounds__(512) void pv_kernel(const u16* __restrict__ S2,
                                                 const u16* __restrict__ Vt2,
                                                 float* __restrict__ out) {
  __shared__ u16 As[3][2][256 * 32];    // [buf][k-half][256 q][32 k]
  __shared__ u16 Bs[3][2][128 * 32];    // [buf][k-half][128 u][32 k]
  __shared__ float larr[256];
  const int id = blockIdx.x;
  const int b = id & 7;                 // batch == XCD
  const int local = id >> 3;            // 0..31
  const int bn = (local & 3) * 128;     // u cols
  const int bm = (local >> 2) * 256;    // q rows

  // S2[b][kt][q][32]: tile base (b,kt,bm) = A2 + kt*65536 (+row*32)
  const u16* A2 = S2 + ((size_t)b * 64 * 2048 + (size_t)bm) * 32;
  // Vt2[b][kt][u][32]: tile base (b,kt,bn) = B2 + kt*16384 (+row*32)
  const u16* B2 = Vt2 + ((size_t)b * 64 * 512 + (size_t)bn) * 32;

  const int t = threadIdx.x;            // 0..511
  const int lane = t & 63;
  const int wid = t >> 6;               // 0..7
  const int wm = wid >> 1;              // 0..3: q 64-row block
  const int wn = wid & 1;               // 0..1: u 64-col block
  const int la = lane & 15;
  const int q = lane >> 4;

  f32x4 acc[4][4] = {};
  float lacc[4] = {0.f, 0.f, 0.f, 0.f};
  bf16x8 a[4][2], bfr[4][2];            // [frag][k-half], static indices

  // one gload_lds per thread per call; part: A it 0..3, B it 0..1
  auto stageA = [&](int s, int it) {
    const int buf = s % 3;
    int c = it * 512 + t;               // 0..2047; h = c>>10 (half)
    int h = c >> 10;
    int idx = c & 1023;
    int row = idx >> 2;
    int col = ((c & 3) ^ ((row >> 1) & 3)) << 3;
    __builtin_amdgcn_global_load_lds(
        (const __attribute__((address_space(1))) void*)(A2 + (size_t)(2 * s + h) * 65536 + row * 32 + col),
        (__attribute__((address_space(3))) void*)(&As[buf][0][c * 8]), 16, 0, 0);
  };
  auto stageB = [&](int s, int it) {
    const int buf = s % 3;
    int c = it * 512 + t;               // 0..1023; h = c>>9 (half)
    int h = c >> 9;
    int idx = c & 511;
    int row = idx >> 2;
    int col = ((c & 3) ^ ((row >> 1) & 3)) << 3;
    __builtin_amdgcn_global_load_lds(
        (const __attribute__((address_space(1))) void*)(B2 + (size_t)(2 * s + h) * 16384 + row * 32 + col),
        (__attribute__((address_space(3))) void*)(&Bs[buf][0][c * 8]), 16, 0, 0);
  };
  auto stage6 = [&](int s) {            // full tile: 6 loads/thread
    stageA(s, 0); stageA(s, 1); stageA(s, 2); stageA(s, 3);
    stageB(s, 0); stageB(s, 1);
  };

  auto rdA = [&](int buf, int i) {
#pragma unroll
    for (int h = 0; h < 2; ++h) {
      int row = wm * 64 + i * 16 + la;
      a[i][h] = *reinterpret_cast<const bf16x8*>(&As[buf][h][row * 32 + ((q ^ ((row >> 1) & 3)) << 3)]);
    }
  };
  auto rdB = [&](int buf, int j) {
#pragma unroll
    for (int h = 0; h < 2; ++h) {
      int row = wn * 64 + j * 16 + la;
      bfr[j][h] = *reinterpret_cast<const bf16x8*>(&Bs[buf][h][row * 32 + ((q ^ ((row >> 1) & 3)) << 3)]);
    }
  };
  auto mm = [&](int i0, int j0) {       // one 32x32 C-quadrant x K=64: 8 MFMA
    __builtin_amdgcn_s_setprio(1);
#pragma unroll
    for (int i = 0; i < 2; ++i)
#pragma unroll
      for (int j = 0; j < 2; ++j)
#pragma unroll
        for (int h = 0; h < 2; ++h)
          acc[i0 + i][j0 + j] =
              __builtin_amdgcn_mfma_f32_16x16x32_bf16(a[i0 + i][h], bfr[j0 + j][h], acc[i0 + i][j0 + j], 0, 0, 0);
    __builtin_amdgcn_s_setprio(0);
  };
  auto lsum = [&](int i0) {             // rowsum: wn==0 counts each P once
    if (wn == 0) {
#pragma unroll
      for (int i = 0; i < 2; ++i) {
        float ls = 0.f;
#pragma unroll
        for (int h = 0; h < 2; ++h)
#pragma unroll
          for (int e = 0; e < 8; ++e) ls += (float)a[i0 + i][h][e];
        lacc[i0 + i] += ls;
      }
    }
  };

  stage6(0); stage6(1);                 // 12 loads/thread in flight
  VMCNT(6); __builtin_amdgcn_s_barrier();   // tile 0 landed (all waves)
  for (int s = 0; s < 30; ++s) {
    const int buf = s % 3;
    // ---- phase 1: quadrant (i01, j01) ----
    rdA(buf, 0); rdA(buf, 1); rdB(buf, 0); rdB(buf, 1);
    stageA(s + 2, 0); stageB(s + 2, 0);
    __builtin_amdgcn_s_barrier();
    mm(0, 0); lsum(0);
    __builtin_amdgcn_s_barrier();
    // ---- phase 2: quadrant (i01, j23) ----
    rdB(buf, 2); rdB(buf, 3);
    stageA(s + 2, 1); stageB(s + 2, 1);
    __builtin_amdgcn_s_barrier();
    mm(0, 2);
    __builtin_amdgcn_s_barrier();
    // ---- phase 3: quadrant (i23, j01) ----
    rdA(buf, 2); rdA(buf, 3);
    stageA(s + 2, 2);
    __builtin_amdgcn_s_barrier();
    mm(2, 0); lsum(2);
    __builtin_amdgcn_s_barrier();
    // ---- phase 4: quadrant (i23, j23) ----
    stageA(s + 2, 3);
    VMCNT(6);                           // tile s+1 landed; s+2's 6 in flight
    __builtin_amdgcn_s_barrier();
    mm(2, 2);
    __builtin_amdgcn_s_barrier();
  }
  {                                     // s = 30 (buf 0), no staging
    const int buf = 0;
    rdA(buf, 0); rdA(buf, 1); rdB(buf, 0); rdB(buf, 1);
    __builtin_amdgcn_s_barrier();
    mm(0, 0); lsum(0);
    __builtin_amdgcn_s_barrier();
    rdB(buf, 2); rdB(buf, 3);
    __builtin_amdgcn_s_barrier();
    mm(0, 2);
    __builtin_amdgcn_s_barrier();
    rdA(buf, 2); rdA(buf, 3);
    __builtin_amdgcn_s_barrier();
    mm(2, 0); lsum(2);
    __builtin_amdgcn_s_barrier();
    VMCNT(0);                           // tile 31 landed
    __builtin_amdgcn_s_barrier();
    mm(2, 2);
    __builtin_amdgcn_s_barrier();
  }
  {                                     // s = 31 (buf 1), no staging/vmcnt
    const int buf = 1;
    rdA(buf, 0); rdA(buf, 1); rdB(buf, 0); rdB(buf, 1);
    __builtin_amdgcn_s_barrier();
    mm(0, 0); lsum(0);
    __builtin_amdgcn_s_barrier();
    rdB(buf, 2); rdB(buf, 3);
    __builtin_amdgcn_s_barrier();
    mm(0, 2);
    __builtin_amdgcn_s_barrier();
    rdA(buf, 2); rdA(buf, 3);
    __builtin_amdgcn_s_barrier();
    mm(2, 0); lsum(2);
    __builtin_amdgcn_s_barrier();
    mm(2, 2);
  }

  // ---- epilogue: reduce row partials over q-lanes, normalize, store ---
  float l[4];
#pragma unroll
  for (int i = 0; i < 4; ++i) {
    l[i] = lacc[i];
    l[i] += __shfl_xor(l[i], 16);
    l[i] += __shfl_xor(l[i], 32);       // sum across 4 q-lanes (la preserved)
  }
  if (wn == 0 && q == 0) {              // writers: 4 wm x 16 la x 4 i = 256 rows
#pragma unroll
    for (int i = 0; i < 4; ++i) larr[wm * 64 + i * 16 + la] = l[i];
  }
  __syncthreads();

  float* C = out + ((size_t)b * 2048 + bm) * 512;
  const int r0 = q * 4, cn = lane & 15;
  float inv[4][4];
#pragma unroll
  for (int i = 0; i < 4; ++i)
#pragma unroll
    for (int r = 0; r < 4; ++r)
      inv[i][r] = 1.0f / larr[wm * 64 + i * 16 + r0 + r];
#pragma unroll
  for (int i = 0; i < 4; ++i)
#pragma unroll
    for (int j = 0; j < 4; ++j)
#pragma unroll
      for (int r = 0; r < 4; ++r) {
        int m = wm * 64 + 16 * i + r0 + r;
        int n = bn + 64 * wn + 16 * j + cn;
        C[(size_t)m * 512 + n] = acc[i][j][r] * inv[i][r];
      }
}

extern "C" void kernel_launch(void* const* d_in, const int* in_sizes, int n_in,
                              void* d_out, int out_size, void* d_ws, size_t ws_size,
                              hipStream_t stream) {
  const float* x  = (const float*)d_in[0];
  const float* Wq = (const float*)d_in[1];
  const float* Wk = (const float*)d_in[2];
  const float* Wv = (const float*)d_in[3];
  float* out = (float*)d_out;

  // ws layout: Xb bf16[16384][512] | Wt bf16[3][512][512] | Q | K | Vt2 | S2
  char* p = (char*)d_ws;
  u16* Xb = (u16*)p;            p += (size_t)16384 * 512 * 2;
  u16* Wt = (u16*)p;            p += (size_t)3 * 512 * 512 * 2;
  u16* Q  = (u16*)p;            p += (size_t)16384 * 512 * 2;
  u16* K  = (u16*)p;            p += (size_t)16384 * 512 * 2;
  u16* Vt2 = (u16*)p;           p += (size_t)16384 * 512 * 2;
  u16* S2 = (u16*)p;

  cast_x_kernel<<<dim3(8192), dim3(256), 0, stream>>>(x, Xb, 16384 * 512 / 4);
  transpose_w_kernel<<<dim3(16, 16, 3), dim3(32, 32), 0, stream>>>(Wq, Wk, Wv, Wt);
  qkv_kernel<<<dim3(4, 128, 3), dim3(256), 0, stream>>>(Xb, Wt, Q, K, Vt2);
  scores8_kernel<<<dim3(8, 8, 8), dim3(512), 0, stream>>>(Q, K, S2);
  pv_kernel<<<dim3(256), dim3(512), 0, stream>>>(S2, Vt2, out);
}

// Round 6
// 142.634 us; speedup vs baseline: 1.0675x; 1.0381x over previous
//
#include <hip/hip_runtime.h>

typedef __attribute__((ext_vector_type(8))) __bf16 bf16x8;
typedef __attribute__((ext_vector_type(4))) float f32x4;
typedef unsigned short u16;
typedef unsigned int u32;

#define VMCNT(n) asm volatile("s_waitcnt vmcnt(" #n ")" ::: "memory")

__device__ __forceinline__ u16 f2bf(float f) {
  union { float f; u32 u; } v; v.f = f;
  u32 r = v.u + 0x7FFFu + ((v.u >> 16) & 1u);
  return (u16)(r >> 16);
}
__device__ __forceinline__ float fexp2(float x) {  // 2^x via v_exp_f32
  float r; asm("v_exp_f32 %0, %1" : "=v"(r) : "v"(x)); return r;
}

// ---------------- cast x fp32 -> bf16 (4 elems/thread) ----------------
__global__ __launch_bounds__(256) void cast_x_kernel(const float* __restrict__ x,
                                                     u16* __restrict__ xb, int n4) {
  int i = blockIdx.x * 256 + threadIdx.x;
  if (i >= n4) return;
  float4 v = reinterpret_cast<const float4*>(x)[i];
  ushort4 o;
  o.x = f2bf(v.x); o.y = f2bf(v.y); o.z = f2bf(v.z); o.w = f2bf(v.w);
  reinterpret_cast<ushort4*>(xb)[i] = o;
}

// ------- transpose weights: Wt[u][d] = W[d][u], fp32 -> bf16 ----------
__global__ __launch_bounds__(1024) void transpose_w_kernel(const float* __restrict__ Wq,
                                                           const float* __restrict__ Wk,
                                                           const float* __restrict__ Wv,
                                                           u16* __restrict__ Wt) {
  const float* src = blockIdx.z == 0 ? Wq : (blockIdx.z == 1 ? Wk : Wv);
  u16* dst = Wt + (size_t)blockIdx.z * 512 * 512;
  __shared__ float tile[32][33];
  int u0 = blockIdx.x * 32, d0 = blockIdx.y * 32;
  tile[threadIdx.y][threadIdx.x] = src[(d0 + threadIdx.y) * 512 + u0 + threadIdx.x];
  __syncthreads();
  dst[(u0 + threadIdx.y) * 512 + d0 + threadIdx.x] = f2bf(tile[threadIdx.x][threadIdx.y]);
}

// ---------------- QKV projection: 128x128 tile, ring-3 counted-vmcnt ----
// z==2 (V) writes Vt2[b][kt][u][32] (kt = s>>5): pv stages contiguous tiles.
__global__ __launch_bounds__(256) void qkv_kernel(const u16* __restrict__ Xb,
                                                  const u16* __restrict__ Wt3,
                                                  u16* __restrict__ Q, u16* __restrict__ K,
                                                  u16* __restrict__ Vt2) {
  __shared__ u16 As[3][128 * 32], Bs[3][128 * 32];
  const int bm = blockIdx.y * 128;
  const int bn = blockIdx.x * 128;
  const int z = blockIdx.z;
  const u16* A = Xb + (size_t)bm * 512;
  const u16* Bt = Wt3 + (size_t)z * 512 * 512 + (size_t)bn * 512;

  const int t = threadIdx.x;
  const int lane = t & 63;
  const int w = t >> 6;
  const int wr = w >> 1, wc = w & 1;
  const int la = lane & 15;
  const int q = lane >> 4;
  f32x4 acc[4][4] = {};

  auto stage = [&](int buf, int kt) {
    const int k0 = kt * 32;
#pragma unroll
    for (int it = 0; it < 2; ++it) {    // A: 128 rows -> 512 chunks
      int c = it * 256 + t, row = c >> 2;
      int col = ((c & 3) ^ ((row >> 1) & 3)) << 3;
      __builtin_amdgcn_global_load_lds(
          (const __attribute__((address_space(1))) void*)(A + (size_t)row * 512 + k0 + col),
          (__attribute__((address_space(3))) void*)(&As[buf][c * 8]), 16, 0, 0);
    }
#pragma unroll
    for (int it = 0; it < 2; ++it) {    // B: 128 rows -> 512 chunks
      int c = it * 256 + t, row = c >> 2;
      int col = ((c & 3) ^ ((row >> 1) & 3)) << 3;
      __builtin_amdgcn_global_load_lds(
          (const __attribute__((address_space(1))) void*)(Bt + (size_t)row * 512 + k0 + col),
          (__attribute__((address_space(3))) void*)(&Bs[buf][c * 8]), 16, 0, 0);
    }
  };

  auto body = [&](int buf) {
    bf16x8 a[4], b[4];
#pragma unroll
    for (int i = 0; i < 4; ++i) {
      int row = wr * 64 + i * 16 + la;
      a[i] = *reinterpret_cast<const bf16x8*>(&As[buf][row * 32 + ((q ^ ((row >> 1) & 3)) << 3)]);
    }
#pragma unroll
    for (int j = 0; j < 4; ++j) {
      int row = wc * 64 + j * 16 + la;
      b[j] = *reinterpret_cast<const bf16x8*>(&Bs[buf][row * 32 + ((q ^ ((row >> 1) & 3)) << 3)]);
    }
    __builtin_amdgcn_s_setprio(1);
#pragma unroll
    for (int i = 0; i < 4; ++i)
#pragma unroll
      for (int j = 0; j < 4; ++j)
        acc[i][j] = __builtin_amdgcn_mfma_f32_16x16x32_bf16(a[i], b[j], acc[i][j], 0, 0, 0);
    __builtin_amdgcn_s_setprio(0);
  };

  stage(0, 0); stage(1, 1);             // 8 loads/thread in flight
  int cb = 0, sb = 2;
  for (int kt = 0; kt < 14; ++kt) {
    VMCNT(4);                           // tile kt landed; kt+1 flying
    __builtin_amdgcn_s_barrier();       // all waves' kt landed; buf sb free
    stage(sb, kt + 2);
    body(cb);
    cb = (cb == 2) ? 0 : cb + 1;
    sb = (sb == 2) ? 0 : sb + 1;
  }
  VMCNT(4); __builtin_amdgcn_s_barrier(); body(2);   // kt=14 -> buf 14%3=2
  VMCNT(0); __builtin_amdgcn_s_barrier(); body(0);   // kt=15 -> buf 0

  const int r0 = q * 4, cn = lane & 15;
  if (z < 2) {
    u16* out = (z == 0) ? Q : K;
#pragma unroll
    for (int i = 0; i < 4; ++i)
#pragma unroll
      for (int j = 0; j < 4; ++j)
#pragma unroll
        for (int r = 0; r < 4; ++r) {
          int m = bm + 64 * wr + 16 * i + r0 + r;
          int n = bn + 64 * wc + 16 * j + cn;
          out[(size_t)m * 512 + n] = f2bf(acc[i][j][r]);
        }
  } else {
#pragma unroll
    for (int i = 0; i < 4; ++i)
#pragma unroll
      for (int j = 0; j < 4; ++j)
#pragma unroll
        for (int r = 0; r < 4; ++r) {
          int m = bm + 64 * wr + 16 * i + r0 + r;
          int u = bn + 64 * wc + 16 * j + cn;
          int b = m >> 11, s = m & 2047;
          // Vt2[b][kt=s>>5][u][s&31]
          Vt2[(((size_t)b * 64 + (s >> 5)) * 512 + u) * 32 + (s & 31)] = f2bf(acc[i][j][r]);
        }
  }
}

// ------ P = exp(Q K^T / sqrt(512)) -> bf16: 256x256, ring-4 ------
// Output layout S2[b][kt][q][32] (kt = k>>5): pv stages contiguous tiles.
__global__ __launch_bounds__(512) void scores8_kernel(const u16* __restrict__ Q,
                                                      const u16* __restrict__ K,
                                                      u16* __restrict__ S2) {
  __shared__ u16 ring[4][2][256 * 32];  // [buf][A=0/B=1][256 rows][32 k]
  const int bb = blockIdx.x;            // batch -> XCD
  const int bm = blockIdx.y * 256;
  const int bn = blockIdx.z * 256;
  const u16* Aq = Q + (size_t)(bb * 2048 + bm) * 512;
  const u16* Bk = K + (size_t)(bb * 2048 + bn) * 512;

  const int t = threadIdx.x;
  const int lane = t & 63;
  const int wid = t >> 6;
  const int wm = wid >> 2, wn = wid & 3;
  const int la = lane & 15;
  const int q = lane >> 4;              // k-slot 0..3 (8 elems each)

  f32x4 acc[8][4] = {};

  auto stage = [&](int kt) {
    const int r = kt & 3;
    const int koff = kt * 32;
#pragma unroll
    for (int half = 0; half < 2; ++half) {
      int c = half * 512 + t;
      int row = c >> 2;
      int col = ((c & 3) ^ ((row >> 1) & 3)) << 3;   // inverse swizzle on source
      __builtin_amdgcn_global_load_lds(
          (const __attribute__((address_space(1))) void*)(Aq + (size_t)row * 512 + koff + col),
          (__attribute__((address_space(3))) void*)(&ring[r][0][c * 8]), 16, 0, 0);
      __builtin_amdgcn_global_load_lds(
          (const __attribute__((address_space(1))) void*)(Bk + (size_t)row * 512 + koff + col),
          (__attribute__((address_space(3))) void*)(&ring[r][1][c * 8]), 16, 0, 0);
    }
  };

  auto body = [&](int kt) {
    const int r = kt & 3;
    const u16* At = ring[r][0];
    const u16* Bt = ring[r][1];
    bf16x8 bfr[4], afr[8];
#pragma unroll
    for (int j = 0; j < 4; ++j) {
      int row = wn * 64 + j * 16 + la;
      bfr[j] = *reinterpret_cast<const bf16x8*>(Bt + row * 32 + ((q ^ ((row >> 1) & 3)) << 3));
    }
#pragma unroll
    for (int i = 0; i < 8; ++i) {
      int row = wm * 128 + i * 16 + la;
      afr[i] = *reinterpret_cast<const bf16x8*>(At + row * 32 + ((q ^ ((row >> 1) & 3)) << 3));
    }
    __builtin_amdgcn_s_setprio(1);
#pragma unroll
    for (int i = 0; i < 8; ++i)
#pragma unroll
      for (int j = 0; j < 4; ++j)
        acc[i][j] = __builtin_amdgcn_mfma_f32_16x16x32_bf16(afr[i], bfr[j], acc[i][j], 0, 0, 0);
    __builtin_amdgcn_s_setprio(0);
  };

  stage(0); stage(1); stage(2);         // 12 loads/thread in flight
  for (int kt = 0; kt < 13; ++kt) {
    VMCNT(8);                           // kt's 4 loads landed; kt+1/kt+2 fly
    __builtin_amdgcn_s_barrier();       // all waves' kt landed; buf[(kt+3)&3] free
    stage(kt + 3);
    body(kt);
  }
  VMCNT(8); __builtin_amdgcn_s_barrier(); body(13);
  VMCNT(4); __builtin_amdgcn_s_barrier(); body(14);
  VMCNT(0); __builtin_amdgcn_s_barrier(); body(15);

  const float scale = 0.06375872127f;   // log2(e)/sqrt(512)
  const int r0h = q * 4;
#pragma unroll
  for (int i = 0; i < 8; ++i)
#pragma unroll
    for (int j = 0; j < 4; ++j) {
      int n = bn + wn * 64 + j * 16;                 // k-col base (la added below)
      int kt_j = n >> 5;
      int ke_j = (n & 31) + la;                      // no carry: (n&31) in {0,16}, la<16
      u16* dst = S2 + ((size_t)(bb * 64 + kt_j) * 2048) * 32 + ke_j;
#pragma unroll
      for (int r = 0; r < 4; ++r) {
        int m = bm + wm * 128 + i * 16 + r0h + r;
        dst[(size_t)m * 32] = f2bf(fexp2(acc[i][j][r] * scale));
      }
    }
}

// ---- out = (P * V) / rowsum(P): 128x128 tile, ring-3, 16 WAVES/CU ----
// Round-5 post-mortem: five schedule variants (ring-3/4, 128^2, 256x128
// BK=64, 8-phase) ALL land at ~60-62us / MfmaUtil ~22% / VALUBusy ~21% /
// Occupancy ~19%. Nothing saturated (MFMA issue ~7%, L2 ~20%, LDS ~17%,
// HBM 15%) => latency/occupancy-bound. The shared parameter was 8
// waves/CU: barrier-locked waves have no independent peer to slip with.
// Fix: 512-thr blocks (8 waves of 32q x 64u) on 128^2 tile, LDS 48.5KB
// -> TWO co-resident blocks/CU (grid 512 = 2/CU) = 16 waves/CU; when one
// block's waves park at vmcnt/barrier, the other block's waves issue
// (m114 cross-block overlap; m97's 912-TF GEMM ran ~12 waves/CU).
// __launch_bounds__(512,4) caps VGPR at 128 so 4 waves/SIMD fit.
__global__ __launch_bounds__(512, 4) void pv_kernel(const u16* __restrict__ S2,
                                                    const u16* __restrict__ Vt2,
                                                    float* __restrict__ out) {
  __shared__ u16 As[3][128 * 32], Bs[3][128 * 32];
  __shared__ float larr[128];
  const int id = blockIdx.x;
  const int b = id & 7;                 // batch == XCD
  const int local = id >> 3;            // 0..63
  const int bn = (local & 3) * 128;     // u cols
  const int bm = (local >> 2) * 128;    // q rows (16 tiles)

  // S2[b][kt][q][32]: tile base (b,kt,bm) = A2 + kt*65536 (+row*32)
  const u16* A2 = S2 + ((size_t)b * 64 * 2048 + (size_t)bm) * 32;
  // Vt2[b][kt][u][32]: tile base (b,kt,bn) = B2 + kt*16384 (+row*32)
  const u16* B2 = Vt2 + ((size_t)b * 64 * 512 + (size_t)bn) * 32;

  const int t = threadIdx.x;            // 0..511
  const int lane = t & 63;
  const int wid = t >> 6;               // 0..7
  const int wm = wid >> 1;              // 0..3: 32-row q block
  const int wn = wid & 1;               // 0..1: 64-col u block
  const int la = lane & 15;
  const int q = lane >> 4;

  f32x4 acc[2][4] = {};
  float lacc[2] = {0.f, 0.f};

  auto stage = [&](int kt) {            // 2 loads/thread (1 A + 1 B)
    const int buf = kt % 3;
    const u16* At = A2 + (size_t)kt * 65536;   // 2048*32
    const u16* Bt = B2 + (size_t)kt * 16384;   // 512*32
    int c = t;                          // 512 chunks: row 0..127, 4 chunks/row
    int row = c >> 2;
    int col = ((c & 3) ^ ((row >> 1) & 3)) << 3;
    __builtin_amdgcn_global_load_lds(
        (const __attribute__((address_space(1))) void*)(At + row * 32 + col),
        (__attribute__((address_space(3))) void*)(&As[buf][c * 8]), 16, 0, 0);
    __builtin_amdgcn_global_load_lds(
        (const __attribute__((address_space(1))) void*)(Bt + row * 32 + col),
        (__attribute__((address_space(3))) void*)(&Bs[buf][c * 8]), 16, 0, 0);
  };

  auto body = [&](int kt) {
    const int buf = kt % 3;
    bf16x8 a[2], bb[4];
#pragma unroll
    for (int i = 0; i < 2; ++i) {
      int row = wm * 32 + i * 16 + la;
      a[i] = *reinterpret_cast<const bf16x8*>(&As[buf][row * 32 + ((q ^ ((row >> 1) & 3)) << 3)]);
    }
    if (wn == 0) {                      // count each P element exactly once
#pragma unroll
      for (int i = 0; i < 2; ++i) {
        float ls = 0.f;
#pragma unroll
        for (int e = 0; e < 8; ++e) ls += (float)a[i][e];
        lacc[i] += ls;
      }
    }
#pragma unroll
    for (int j = 0; j < 4; ++j) {
      int row = wn * 64 + j * 16 + la;
      bb[j] = *reinterpret_cast<const bf16x8*>(&Bs[buf][row * 32 + ((q ^ ((row >> 1) & 3)) << 3)]);
    }
    __builtin_amdgcn_s_setprio(1);
#pragma unroll
    for (int i = 0; i < 2; ++i)
#pragma unroll
      for (int j = 0; j < 4; ++j)
        acc[i][j] = __builtin_amdgcn_mfma_f32_16x16x32_bf16(a[i], bb[j], acc[i][j], 0, 0, 0);
    __builtin_amdgcn_s_setprio(0);
  };

  stage(0); stage(1);                   // 4 loads/thread in flight
  for (int kt = 0; kt < 62; ++kt) {
    VMCNT(2);                           // tile kt landed; kt+1 flying
    __builtin_amdgcn_s_barrier();       // all waves' kt landed; buf (kt+2)%3 free
    stage(kt + 2);
    body(kt);
  }
  VMCNT(2); __builtin_amdgcn_s_barrier(); body(62);
  VMCNT(0); __builtin_amdgcn_s_barrier(); body(63);

  // ---- epilogue: reduce row partials over q-lanes, normalize, store ---
  float l[2];
#pragma unroll
  for (int i = 0; i < 2; ++i) {
    l[i] = lacc[i];
    l[i] += __shfl_xor(l[i], 16);
    l[i] += __shfl_xor(l[i], 32);       // sum across 4 q-lanes (la preserved)
  }
  if (wn == 0 && q == 0) {              // writers: 4 wm x 2 i x 16 la = 128 rows
#pragma unroll
    for (int i = 0; i < 2; ++i) larr[wm * 32 + i * 16 + la] = l[i];
  }
  __syncthreads();

  float* C = out + ((size_t)b * 2048 + bm) * 512;
  const int r0 = q * 4, cn = lane & 15;
  float inv[2][4];
#pragma unroll
  for (int i = 0; i < 2; ++i)
#pragma unroll
    for (int r = 0; r < 4; ++r)
      inv[i][r] = 1.0f / larr[wm * 32 + i * 16 + r0 + r];
#pragma unroll
  for (int i = 0; i < 2; ++i)
#pragma unroll
    for (int j = 0; j < 4; ++j)
#pragma unroll
      for (int r = 0; r < 4; ++r) {
        int m = wm * 32 + 16 * i + r0 + r;
        int n = bn + 64 * wn + 16 * j + cn;
        C[(size_t)m * 512 + n] = acc[i][j][r] * inv[i][r];
      }
}

extern "C" void kernel_launch(void* const* d_in, const int* in_sizes, int n_in,
                              void* d_out, int out_size, void* d_ws, size_t ws_size,
                              hipStream_t stream) {
  const float* x  = (const float*)d_in[0];
  const float* Wq = (const float*)d_in[1];
  const float* Wk = (const float*)d_in[2];
  const float* Wv = (const float*)d_in[3];
  float* out = (float*)d_out;

  // ws layout: Xb bf16[16384][512] | Wt bf16[3][512][512] | Q | K | Vt2 | S2
  char* p = (char*)d_ws;
  u16* Xb = (u16*)p;            p += (size_t)16384 * 512 * 2;
  u16* Wt = (u16*)p;            p += (size_t)3 * 512 * 512 * 2;
  u16* Q  = (u16*)p;            p += (size_t)16384 * 512 * 2;
  u16* K  = (u16*)p;            p += (size_t)16384 * 512 * 2;
  u16* Vt2 = (u16*)p;           p += (size_t)16384 * 512 * 2;
  u16* S2 = (u16*)p;

  cast_x_kernel<<<dim3(8192), dim3(256), 0, stream>>>(x, Xb, 16384 * 512 / 4);
  transpose_w_kernel<<<dim3(16, 16, 3), dim3(32, 32), 0, stream>>>(Wq, Wk, Wv, Wt);
  qkv_kernel<<<dim3(4, 128, 3), dim3(256), 0, stream>>>(Xb, Wt, Q, K, Vt2);
  scores8_kernel<<<dim3(8, 8, 8), dim3(512), 0, stream>>>(Q, K, S2);
  pv_kernel<<<dim3(512), dim3(512), 0, stream>>>(S2, Vt2, out);
}

// Round 7
// 140.202 us; speedup vs baseline: 1.0860x; 1.0173x over previous
//
#include <hip/hip_runtime.h>

typedef __attribute__((ext_vector_type(8))) __bf16 bf16x8;
typedef __attribute__((ext_vector_type(4))) float f32x4;
typedef unsigned short u16;
typedef unsigned int u32;

#define VMCNT(n) asm volatile("s_waitcnt vmcnt(" #n ")" ::: "memory")
#define LGKMCNT0 asm volatile("s_waitcnt lgkmcnt(0)" ::: "memory")

__device__ __forceinline__ u16 f2bf(float f) {
  union { float f; u32 u; } v; v.f = f;
  u32 r = v.u + 0x7FFFu + ((v.u >> 16) & 1u);
  return (u16)(r >> 16);
}
__device__ __forceinline__ float fexp2(float x) {  // 2^x via v_exp_f32
  float r; asm("v_exp_f32 %0, %1" : "=v"(r) : "v"(x)); return r;
}

// ---------------- cast x fp32 -> bf16 (4 elems/thread) ----------------
__global__ __launch_bounds__(256) void cast_x_kernel(const float* __restrict__ x,
                                                     u16* __restrict__ xb, int n4) {
  int i = blockIdx.x * 256 + threadIdx.x;
  if (i >= n4) return;
  float4 v = reinterpret_cast<const float4*>(x)[i];
  ushort4 o;
  o.x = f2bf(v.x); o.y = f2bf(v.y); o.z = f2bf(v.z); o.w = f2bf(v.w);
  reinterpret_cast<ushort4*>(xb)[i] = o;
}

// ------- transpose weights: Wt[u][d] = W[d][u], fp32 -> bf16 ----------
__global__ __launch_bounds__(1024) void transpose_w_kernel(const float* __restrict__ Wq,
                                                           const float* __restrict__ Wk,
                                                           const float* __restrict__ Wv,
                                                           u16* __restrict__ Wt) {
  const float* src = blockIdx.z == 0 ? Wq : (blockIdx.z == 1 ? Wk : Wv);
  u16* dst = Wt + (size_t)blockIdx.z * 512 * 512;
  __shared__ float tile[32][33];
  int u0 = blockIdx.x * 32, d0 = blockIdx.y * 32;
  tile[threadIdx.y][threadIdx.x] = src[(d0 + threadIdx.y) * 512 + u0 + threadIdx.x];
  __syncthreads();
  dst[(u0 + threadIdx.y) * 512 + d0 + threadIdx.x] = f2bf(tile[threadIdx.x][threadIdx.y]);
}

// ---------------- QKV projection: 128x128 tile, ring-3 counted-vmcnt ----
// z==2 (V) writes Vt2[b][kt][u][32] (kt = s>>5): pv stages contiguous tiles.
__global__ __launch_bounds__(256) void qkv_kernel(const u16* __restrict__ Xb,
                                                  const u16* __restrict__ Wt3,
                                                  u16* __restrict__ Q, u16* __restrict__ K,
                                                  u16* __restrict__ Vt2) {
  __shared__ u16 As[3][128 * 32], Bs[3][128 * 32];
  const int bm = blockIdx.y * 128;
  const int bn = blockIdx.x * 128;
  const int z = blockIdx.z;
  const u16* A = Xb + (size_t)bm * 512;
  const u16* Bt = Wt3 + (size_t)z * 512 * 512 + (size_t)bn * 512;

  const int t = threadIdx.x;
  const int lane = t & 63;
  const int w = t >> 6;
  const int wr = w >> 1, wc = w & 1;
  const int la = lane & 15;
  const int q = lane >> 4;
  f32x4 acc[4][4] = {};

  auto stage = [&](int buf, int kt) {
    const int k0 = kt * 32;
#pragma unroll
    for (int it = 0; it < 2; ++it) {    // A: 128 rows -> 512 chunks
      int c = it * 256 + t, row = c >> 2;
      int col = ((c & 3) ^ ((row >> 1) & 3)) << 3;
      __builtin_amdgcn_global_load_lds(
          (const __attribute__((address_space(1))) void*)(A + (size_t)row * 512 + k0 + col),
          (__attribute__((address_space(3))) void*)(&As[buf][c * 8]), 16, 0, 0);
    }
#pragma unroll
    for (int it = 0; it < 2; ++it) {    // B: 128 rows -> 512 chunks
      int c = it * 256 + t, row = c >> 2;
      int col = ((c & 3) ^ ((row >> 1) & 3)) << 3;
      __builtin_amdgcn_global_load_lds(
          (const __attribute__((address_space(1))) void*)(Bt + (size_t)row * 512 + k0 + col),
          (__attribute__((address_space(3))) void*)(&Bs[buf][c * 8]), 16, 0, 0);
    }
  };

  auto body = [&](int buf) {
    bf16x8 a[4], b[4];
#pragma unroll
    for (int i = 0; i < 4; ++i) {
      int row = wr * 64 + i * 16 + la;
      a[i] = *reinterpret_cast<const bf16x8*>(&As[buf][row * 32 + ((q ^ ((row >> 1) & 3)) << 3)]);
    }
#pragma unroll
    for (int j = 0; j < 4; ++j) {
      int row = wc * 64 + j * 16 + la;
      b[j] = *reinterpret_cast<const bf16x8*>(&Bs[buf][row * 32 + ((q ^ ((row >> 1) & 3)) << 3)]);
    }
    __builtin_amdgcn_s_setprio(1);
#pragma unroll
    for (int i = 0; i < 4; ++i)
#pragma unroll
      for (int j = 0; j < 4; ++j)
        acc[i][j] = __builtin_amdgcn_mfma_f32_16x16x32_bf16(a[i], b[j], acc[i][j], 0, 0, 0);
    __builtin_amdgcn_s_setprio(0);
  };

  stage(0, 0); stage(1, 1);             // 8 loads/thread in flight
  int cb = 0, sb = 2;
  for (int kt = 0; kt < 14; ++kt) {
    VMCNT(4);                           // tile kt landed; kt+1 flying
    __builtin_amdgcn_s_barrier();       // all waves' kt landed; buf sb free
    stage(sb, kt + 2);
    body(cb);
    cb = (cb == 2) ? 0 : cb + 1;
    sb = (sb == 2) ? 0 : sb + 1;
  }
  VMCNT(4); __builtin_amdgcn_s_barrier(); body(2);   // kt=14 -> buf 14%3=2
  VMCNT(0); __builtin_amdgcn_s_barrier(); body(0);   // kt=15 -> buf 0

  const int r0 = q * 4, cn = lane & 15;
  if (z < 2) {
    u16* out = (z == 0) ? Q : K;
#pragma unroll
    for (int i = 0; i < 4; ++i)
#pragma unroll
      for (int j = 0; j < 4; ++j)
#pragma unroll
        for (int r = 0; r < 4; ++r) {
          int m = bm + 64 * wr + 16 * i + r0 + r;
          int n = bn + 64 * wc + 16 * j + cn;
          out[(size_t)m * 512 + n] = f2bf(acc[i][j][r]);
        }
  } else {
#pragma unroll
    for (int i = 0; i < 4; ++i)
#pragma unroll
      for (int j = 0; j < 4; ++j)
#pragma unroll
        for (int r = 0; r < 4; ++r) {
          int m = bm + 64 * wr + 16 * i + r0 + r;
          int u = bn + 64 * wc + 16 * j + cn;
          int b = m >> 11, s = m & 2047;
          // Vt2[b][kt=s>>5][u][s&31]
          Vt2[(((size_t)b * 64 + (s >> 5)) * 512 + u) * 32 + (s & 31)] = f2bf(acc[i][j][r]);
        }
  }
}

// ------ P = exp(Q K^T / sqrt(512)) -> bf16: 256x256, ring-4 ------
// Output layout S2[b][kt][q][32] (kt = k>>5): pv stages contiguous tiles.
__global__ __launch_bounds__(512) void scores8_kernel(const u16* __restrict__ Q,
                                                      const u16* __restrict__ K,
                                                      u16* __restrict__ S2) {
  __shared__ u16 ring[4][2][256 * 32];  // [buf][A=0/B=1][256 rows][32 k]
  const int bb = blockIdx.x;            // batch -> XCD
  const int bm = blockIdx.y * 256;
  const int bn = blockIdx.z * 256;
  const u16* Aq = Q + (size_t)(bb * 2048 + bm) * 512;
  const u16* Bk = K + (size_t)(bb * 2048 + bn) * 512;

  const int t = threadIdx.x;
  const int lane = t & 63;
  const int wid = t >> 6;
  const int wm = wid >> 2, wn = wid & 3;
  const int la = lane & 15;
  const int q = lane >> 4;              // k-slot 0..3 (8 elems each)

  f32x4 acc[8][4] = {};

  auto stage = [&](int kt) {
    const int r = kt & 3;
    const int koff = kt * 32;
#pragma unroll
    for (int half = 0; half < 2; ++half) {
      int c = half * 512 + t;
      int row = c >> 2;
      int col = ((c & 3) ^ ((row >> 1) & 3)) << 3;   // inverse swizzle on source
      __builtin_amdgcn_global_load_lds(
          (const __attribute__((address_space(1))) void*)(Aq + (size_t)row * 512 + koff + col),
          (__attribute__((address_space(3))) void*)(&ring[r][0][c * 8]), 16, 0, 0);
      __builtin_amdgcn_global_load_lds(
          (const __attribute__((address_space(1))) void*)(Bk + (size_t)row * 512 + koff + col),
          (__attribute__((address_space(3))) void*)(&ring[r][1][c * 8]), 16, 0, 0);
    }
  };

  auto body = [&](int kt) {
    const int r = kt & 3;
    const u16* At = ring[r][0];
    const u16* Bt = ring[r][1];
    bf16x8 bfr[4], afr[8];
#pragma unroll
    for (int j = 0; j < 4; ++j) {
      int row = wn * 64 + j * 16 + la;
      bfr[j] = *reinterpret_cast<const bf16x8*>(Bt + row * 32 + ((q ^ ((row >> 1) & 3)) << 3));
    }
#pragma unroll
    for (int i = 0; i < 8; ++i) {
      int row = wm * 128 + i * 16 + la;
      afr[i] = *reinterpret_cast<const bf16x8*>(At + row * 32 + ((q ^ ((row >> 1) & 3)) << 3));
    }
    __builtin_amdgcn_s_setprio(1);
#pragma unroll
    for (int i = 0; i < 8; ++i)
#pragma unroll
      for (int j = 0; j < 4; ++j)
        acc[i][j] = __builtin_amdgcn_mfma_f32_16x16x32_bf16(afr[i], bfr[j], acc[i][j], 0, 0, 0);
    __builtin_amdgcn_s_setprio(0);
  };

  stage(0); stage(1); stage(2);         // 12 loads/thread in flight
  for (int kt = 0; kt < 13; ++kt) {
    VMCNT(8);                           // kt's 4 loads landed; kt+1/kt+2 fly
    __builtin_amdgcn_s_barrier();       // all waves' kt landed; buf[(kt+3)&3] free
    stage(kt + 3);
    body(kt);
  }
  VMCNT(8); __builtin_amdgcn_s_barrier(); body(13);
  VMCNT(4); __builtin_amdgcn_s_barrier(); body(14);
  VMCNT(0); __builtin_amdgcn_s_barrier(); body(15);

  const float scale = 0.06375872127f;   // log2(e)/sqrt(512)
  const int r0h = q * 4;
#pragma unroll
  for (int i = 0; i < 8; ++i)
#pragma unroll
    for (int j = 0; j < 4; ++j) {
      int n = bn + wn * 64 + j * 16;                 // k-col base (la added below)
      int kt_j = n >> 5;
      int ke_j = (n & 31) + la;                      // no carry: (n&31) in {0,16}, la<16
      u16* dst = S2 + ((size_t)(bb * 64 + kt_j) * 2048) * 32 + ke_j;
#pragma unroll
      for (int r = 0; r < 4; ++r) {
        int m = bm + wm * 128 + i * 16 + r0h + r;
        dst[(size_t)m * 32] = f2bf(fexp2(acc[i][j][r] * scale));
      }
    }
}

// ---- out = (P * V) / rowsum(P): 128x128, BK=64, k-split waves, ring-2 ----
// Round-6 post-mortem: 16 waves/CU helped (62->55us) but MfmaUtil only 25%:
// LDS-read traffic is now the largest term (0.75 ds_read/MFMA at 32x64
// wave tiles ~= 31us of 55). This version keeps 16 waves/CU AND restores
// 0.5 reads/MFMA: 8 waves = 2(wm) x 2(wn) x 2(wk); each wave computes the
// full 64x64 quadrant over its own 32-k half of each BK=64 step (a[4]+b[4]
// reads -> 16 MFMA). wk-pairs reduce partial acc through LDS once at end.
// Ring-2 (64KB LDS) -> 2 blocks/CU. 8-slot XOR swizzle (pslot=lslot^(row&7))
// keeps ds_read conflict-free at 128B row stride. launch_bounds(512,4)
// caps VGPR at 128 (est ~110) so 4 waves/SIMD fit.
__global__ __launch_bounds__(512, 4) void pv_kernel(const u16* __restrict__ S2,
                                                    const u16* __restrict__ Vt2,
                                                    float* __restrict__ out) {
  __shared__ __align__(16) char smem[65536];      // As[2][8192] | Bs[2][8192] u16
  __shared__ float larr2[2][128];                 // rowsum halves (per wk)
  u16* As = (u16*)smem;                           // [2][128*64]
  u16* Bs = As + 2 * 8192;                        // [2][128*64]
  float* scratch = (float*)smem;                  // epilogue overlay (64KB)

  const int id = blockIdx.x;
  const int b = id & 7;                 // batch == XCD
  const int local = id >> 3;            // 0..63
  const int bn = (local & 3) * 128;     // u cols
  const int bm = (local >> 2) * 128;    // q rows

  // S2[b][kt][q][32]: tile base (b,kt,bm) = A2 + kt*65536 (+row*32)
  const u16* A2 = S2 + ((size_t)b * 64 * 2048 + (size_t)bm) * 32;
  // Vt2[b][kt][u][32]: tile base (b,kt,bn) = B2 + kt*16384 (+row*32)
  const u16* B2 = Vt2 + ((size_t)b * 64 * 512 + (size_t)bn) * 32;

  const int t = threadIdx.x;            // 0..511
  const int lane = t & 63;
  const int wid = t >> 6;               // 0..7
  const int wm = (wid >> 2) & 1;        // q 64-row block
  const int wn = (wid >> 1) & 1;        // u 64-col block
  const int wk = wid & 1;               // k half (32 of each BK=64)
  const int la = lane & 15;
  const int q = lane >> 4;

  f32x4 acc[4][4] = {};
  float lacc[4] = {0.f, 0.f, 0.f, 0.f};

  // stage step s = k-tiles 2s,2s+1 into buf s&1. 4 loads/thread.
  // LDS chunk c: row=c>>3, pslot=c&7; global lslot = pslot ^ (row&7);
  // lslot = h*4 + sl -> source tile kt=2s+h, 8-elem slot sl.
  auto stage = [&](int s) {
    const int buf = s & 1;
#pragma unroll
    for (int it = 0; it < 2; ++it) {    // A: 1024 chunks
      int c = it * 512 + t;
      int row = c >> 3, pslot = c & 7;
      int lslot = pslot ^ (row & 7);
      __builtin_amdgcn_global_load_lds(
          (const __attribute__((address_space(1))) void*)(
              A2 + (size_t)(2 * s + (lslot >> 2)) * 65536 + row * 32 + (lslot & 3) * 8),
          (__attribute__((address_space(3))) void*)(As + buf * 8192 + c * 8), 16, 0, 0);
    }
#pragma unroll
    for (int it = 0; it < 2; ++it) {    // B: 1024 chunks
      int c = it * 512 + t;
      int row = c >> 3, pslot = c & 7;
      int lslot = pslot ^ (row & 7);
      __builtin_amdgcn_global_load_lds(
          (const __attribute__((address_space(1))) void*)(
              B2 + (size_t)(2 * s + (lslot >> 2)) * 16384 + row * 32 + (lslot & 3) * 8),
          (__attribute__((address_space(3))) void*)(Bs + buf * 8192 + c * 8), 16, 0, 0);
    }
  };

  bf16x8 a[4], bb[4];
  auto rd = [&](int buf) {              // 8 ds_read_b128, wave's k-half only
    const u16* Ab = As + buf * 8192;
    const u16* Bb = Bs + buf * 8192;
#pragma unroll
    for (int i = 0; i < 4; ++i) {
      int row = wm * 64 + i * 16 + la;
      int ps = (wk * 4 + q) ^ (row & 7);
      a[i] = *reinterpret_cast<const bf16x8*>(Ab + row * 64 + ps * 8);
    }
#pragma unroll
    for (int j = 0; j < 4; ++j) {
      int row = wn * 64 + j * 16 + la;
      int ps = (wk * 4 + q) ^ (row & 7);
      bb[j] = *reinterpret_cast<const bf16x8*>(Bb + row * 64 + ps * 8);
    }
  };
  auto compute = [&]() {
    if (wn == 0) {                      // rowsum: wk halves partition k
#pragma unroll
      for (int i = 0; i < 4; ++i) {
        float ls = 0.f;
#pragma unroll
        for (int e = 0; e < 8; ++e) ls += (float)a[i][e];
        lacc[i] += ls;
      }
    }
    __builtin_amdgcn_s_setprio(1);
#pragma unroll
    for (int i = 0; i < 4; ++i)
#pragma unroll
      for (int j = 0; j < 4; ++j)
        acc[i][j] = __builtin_amdgcn_mfma_f32_16x16x32_bf16(a[i], bb[j], acc[i][j], 0, 0, 0);
    __builtin_amdgcn_s_setprio(0);
  };

  stage(0); stage(1);                   // 8 loads/thread in flight
  for (int s = 0; s < 30; ++s) {
    VMCNT(4);                           // step s landed; s+1 flying
    __builtin_amdgcn_s_barrier();       // all waves see buf s&1 full
    rd(s & 1);                          // ds_reads of current buf
    LGKMCNT0;                           // my reads landed in regs
    __builtin_amdgcn_s_barrier();       // all waves' reads done -> buf free
    stage(s + 2);                       // overwrite buf s&1
    compute();
  }
  VMCNT(4); __builtin_amdgcn_s_barrier();            // step 30 (buf 0)
  rd(0); LGKMCNT0; __builtin_amdgcn_s_barrier(); compute();
  VMCNT(0); __builtin_amdgcn_s_barrier();            // step 31 (buf 1)
  rd(1); LGKMCNT0; __builtin_amdgcn_s_barrier();     // all reads done pre-overlay
  compute();

  // ---- epilogue: rowsum halves + wk-pair acc reduction via LDS ------
  float l[4];
#pragma unroll
  for (int i = 0; i < 4; ++i) {
    l[i] = lacc[i];
    l[i] += __shfl_xor(l[i], 16);
    l[i] += __shfl_xor(l[i], 32);       // sum across 4 q-lanes (la preserved)
  }
  if (wn == 0 && q == 0) {              // 2 wm x 2 wk waves x 16 la x 4 i
#pragma unroll
    for (int i = 0; i < 4; ++i) larr2[wk][wm * 64 + i * 16 + la] = l[i];
  }
  float* sp = scratch + (wid >> 1) * 4096;   // 16KB per (wm,wn) pair
  if (wk == 1) {
#pragma unroll
    for (int i = 0; i < 4; ++i)
#pragma unroll
      for (int j = 0; j < 4; ++j)
        *reinterpret_cast<f32x4*>(sp + (i * 4 + j) * 256 + lane * 4) = acc[i][j];
  }
  __syncthreads();
  if (wk == 0) {
#pragma unroll
    for (int i = 0; i < 4; ++i)
#pragma unroll
      for (int j = 0; j < 4; ++j) {
        f32x4 o = *reinterpret_cast<const f32x4*>(sp + (i * 4 + j) * 256 + lane * 4);
#pragma unroll
        for (int r = 0; r < 4; ++r) acc[i][j][r] += o[r];
      }
    float* C = out + ((size_t)b * 2048 + bm) * 512;
    const int r0 = q * 4, cn = lane & 15;
    float inv[4][4];
#pragma unroll
    for (int i = 0; i < 4; ++i)
#pragma unroll
      for (int r = 0; r < 4; ++r) {
        int row = wm * 64 + i * 16 + r0 + r;
        inv[i][r] = 1.0f / (larr2[0][row] + larr2[1][row]);
      }
#pragma unroll
    for (int i = 0; i < 4; ++i)
#pragma unroll
      for (int j = 0; j < 4; ++j)
#pragma unroll
        for (int r = 0; r < 4; ++r) {
          int m = wm * 64 + 16 * i + r0 + r;
          int n = bn + 64 * wn + 16 * j + cn;
          C[(size_t)m * 512 + n] = acc[i][j][r] * inv[i][r];
        }
  }
}

extern "C" void kernel_launch(void* const* d_in, const int* in_sizes, int n_in,
                              void* d_out, int out_size, void* d_ws, size_t ws_size,
                              hipStream_t stream) {
  const float* x  = (const float*)d_in[0];
  const float* Wq = (const float*)d_in[1];
  const float* Wk = (const float*)d_in[2];
  const float* Wv = (const float*)d_in[3];
  float* out = (float*)d_out;

  // ws layout: Xb bf16[16384][512] | Wt bf16[3][512][512] | Q | K | Vt2 | S2
  char* p = (char*)d_ws;
  u16* Xb = (u16*)p;            p += (size_t)16384 * 512 * 2;
  u16* Wt = (u16*)p;            p += (size_t)3 * 512 * 512 * 2;
  u16* Q  = (u16*)p;            p += (size_t)16384 * 512 * 2;
  u16* K  = (u16*)p;            p += (size_t)16384 * 512 * 2;
  u16* Vt2 = (u16*)p;           p += (size_t)16384 * 512 * 2;
  u16* S2 = (u16*)p;

  cast_x_kernel<<<dim3(8192), dim3(256), 0, stream>>>(x, Xb, 16384 * 512 / 4);
  transpose_w_kernel<<<dim3(16, 16, 3), dim3(32, 32), 0, stream>>>(Wq, Wk, Wv, Wt);
  qkv_kernel<<<dim3(4, 128, 3), dim3(256), 0, stream>>>(Xb, Wt, Q, K, Vt2);
  scores8_kernel<<<dim3(8, 8, 8), dim3(512), 0, stream>>>(Q, K, S2);
  pv_kernel<<<dim3(512), dim3(512), 0, stream>>>(S2, Vt2, out);
}